// Round 4
// baseline (199.962 us; speedup 1.0000x reference)
//
#include <hip/hip_runtime.h>

typedef unsigned short u16;
typedef unsigned int u32;
typedef short v8s __attribute__((ext_vector_type(8)));
typedef float f32x4 __attribute__((ext_vector_type(4)));
typedef float f32x16 __attribute__((ext_vector_type(16)));

#define S_LEN 4096
#define DM 1024
#define HDIM 64
#define CEXP 0.18033688f /* 0.125 * log2(e), folded into Q at GEMM epilogue */

// ---- helpers ----------------------------------------------------------
__device__ __forceinline__ u16 f2bs(float f) {
  u32 u = __float_as_uint(f);
  u32 r = 0x7FFFu + ((u >> 16) & 1u);
  return (u16)((u + r) >> 16);
}

__device__ __forceinline__ void gstage16(const void* g, void* lds_wave_base) {
  __builtin_amdgcn_global_load_lds(
      (const __attribute__((address_space(1))) u32*)g,
      (__attribute__((address_space(3))) u32*)lds_wave_base, 16, 0, 0);
}

__device__ __forceinline__ f32x16 vzero16() {
  f32x16 v;
#pragma unroll
  for (int r = 0; r < 16; ++r) v[r] = 0.f;
  return v;
}

// ---- elementwise fp32 -> bf16 -----------------------------------------
__global__ void k_cvt(const float* __restrict__ in, u16* __restrict__ out) {
  const int i = blockIdx.x * blockDim.x + threadIdx.x;
  const float4* p = reinterpret_cast<const float4*>(in) + (size_t)i * 2;
  float4 a = p[0], b = p[1];
  u16 t[8] = {f2bs(a.x), f2bs(a.y), f2bs(a.z), f2bs(a.w),
              f2bs(b.x), f2bs(b.y), f2bs(b.z), f2bs(b.w)};
  reinterpret_cast<uint4*>(out)[i] = *reinterpret_cast<const uint4*>(t);
}

// ---- weight transpose+convert: w[K][N] fp32 -> wt[N][K] bf16 ----------
__global__ __launch_bounds__(256) void k_wtrans(
    const float* __restrict__ w0, const float* __restrict__ w1,
    const float* __restrict__ w2, const float* __restrict__ w3,
    u16* __restrict__ t0, u16* __restrict__ t1,
    u16* __restrict__ t2, u16* __restrict__ t3) {
  __shared__ float tile[32][33];
  const float* w; u16* wt;
  switch (blockIdx.z) {
    case 0: w = w0; wt = t0; break;
    case 1: w = w1; wt = t1; break;
    case 2: w = w2; wt = t2; break;
    default: w = w3; wt = t3; break;
  }
  const int r = threadIdx.x >> 3;
  const int c4 = (threadIdx.x & 7) * 4;
  const int k0 = blockIdx.x * 32, n0 = blockIdx.y * 32;
  float4 v = *reinterpret_cast<const float4*>(w + (size_t)(k0 + r) * DM + n0 + c4);
  tile[r][c4] = v.x; tile[r][c4 + 1] = v.y; tile[r][c4 + 2] = v.z; tile[r][c4 + 3] = v.w;
  __syncthreads();
  u16 o4[4] = {f2bs(tile[c4][r]), f2bs(tile[c4 + 1][r]),
               f2bs(tile[c4 + 2][r]), f2bs(tile[c4 + 3][r])};
  *reinterpret_cast<uint2*>(wt + (size_t)(n0 + r) * DM + k0 + c4) =
      *reinterpret_cast<const uint2*>(o4);
}

// ---- GEMM core: C[M=4096,N=1024] = A[bf16, M,K] @ Bt[bf16, N,K]^T + bias
template <int MODE>
__device__ __forceinline__ void gemm_core(
    u16* __restrict__ As, u16* __restrict__ Bs,
    const u16* __restrict__ A, const u16* __restrict__ Bt,
    const float* __restrict__ bias, void* __restrict__ Cout, float oscale) {
  constexpr int K = DM, N = DM;
  const int tid = threadIdx.x;
  const int lane = tid & 63, wave = tid >> 6;
  const int wm = wave >> 1, wn = wave & 1;
  const int l15 = lane & 15, l4 = lane >> 4;
  const int bm0 = blockIdx.x * 128, bn0 = blockIdx.y * 128;

  f32x4 acc[4][4];
#pragma unroll
  for (int m = 0; m < 4; ++m)
#pragma unroll
    for (int n = 0; n < 4; ++n) acc[m][n] = 0.f;

  const int s0 = tid, s1 = tid + 256;
  const int ra0 = s0 >> 2, ca0 = ((s0 & 3) ^ ((ra0 >> 1) & 3)) * 8;
  const int ra1 = s1 >> 2, ca1 = ((s1 & 3) ^ ((ra1 >> 1) & 3)) * 8;
  const u16* Ab = A + (size_t)bm0 * K;
  const u16* Bb = Bt + (size_t)bn0 * K;
  u16* ldsA0 = As + (size_t)(wave * 64) * 8;
  u16* ldsA1 = As + (size_t)(256 + wave * 64) * 8;
  u16* ldsB0 = Bs + (size_t)(wave * 64) * 8;
  u16* ldsB1 = Bs + (size_t)(256 + wave * 64) * 8;

  for (int k0 = 0; k0 < K; k0 += 32) {
    gstage16(Ab + (size_t)ra0 * K + k0 + ca0, ldsA0);
    gstage16(Ab + (size_t)ra1 * K + k0 + ca1, ldsA1);
    gstage16(Bb + (size_t)ra0 * K + k0 + ca0, ldsB0);
    gstage16(Bb + (size_t)ra1 * K + k0 + ca1, ldsB1);
    __syncthreads();
    v8s af[4], bfr[4];
#pragma unroll
    for (int m = 0; m < 4; ++m) {
      const int rowa = wm * 64 + m * 16 + l15;
      af[m] = *reinterpret_cast<const v8s*>(
          As + (size_t)(rowa * 4 + (l4 ^ ((rowa >> 1) & 3))) * 8);
      const int rowb = wn * 64 + m * 16 + l15;
      bfr[m] = *reinterpret_cast<const v8s*>(
          Bs + (size_t)(rowb * 4 + (l4 ^ ((rowb >> 1) & 3))) * 8);
    }
#pragma unroll
    for (int m = 0; m < 4; ++m)
#pragma unroll
      for (int n = 0; n < 4; ++n)
        acc[m][n] = __builtin_amdgcn_mfma_f32_16x16x32_bf16(af[m], bfr[n], acc[m][n], 0, 0, 0);
    __syncthreads();
  }

#pragma unroll
  for (int m = 0; m < 4; ++m) {
    const int gs0 = bm0 + wm * 64 + m * 16 + l4 * 4;
#pragma unroll
    for (int n = 0; n < 4; ++n) {
      const int gn = bn0 + wn * 64 + n * 16 + l15;
      const float bv = bias[gn];
      if (MODE == 0) {
        u16* O = (u16*)Cout;
        const size_t base = (size_t)(gn >> 6) * (S_LEN * HDIM) + (size_t)(gn & 63);
#pragma unroll
        for (int r = 0; r < 4; ++r)
          O[base + (size_t)(gs0 + r) * HDIM] = f2bs((acc[m][n][r] + bv) * oscale);
      } else if (MODE == 1) {
        u16* O = (u16*)Cout;
        u16 p4[4];
#pragma unroll
        for (int r = 0; r < 4; ++r) p4[r] = f2bs(acc[m][n][r] + bv);
        *reinterpret_cast<uint2*>(O + (size_t)(gn >> 6) * (HDIM * S_LEN) +
                                  (size_t)(gn & 63) * S_LEN + gs0) =
            *reinterpret_cast<const uint2*>(p4);
      } else {
        float* O = (float*)Cout;
#pragma unroll
        for (int r = 0; r < 4; ++r)
          O[(size_t)(gs0 + r) * N + gn] = acc[m][n][r] + bv;
      }
    }
  }
}

__global__ __launch_bounds__(256) void k_gemm_qkv(
    const u16* __restrict__ A,
    const u16* __restrict__ wq, const u16* __restrict__ wk, const u16* __restrict__ wv,
    const float* __restrict__ bq, const float* __restrict__ bk, const float* __restrict__ bv,
    u16* __restrict__ Qo, u16* __restrict__ Ko, u16* __restrict__ Vo) {
  __shared__ __attribute__((aligned(16))) u16 As[128 * 32];
  __shared__ __attribute__((aligned(16))) u16 Bs[128 * 32];
  const int z = blockIdx.z;
  if (z == 0)      gemm_core<0>(As, Bs, A, wq, bq, Qo, CEXP);
  else if (z == 1) gemm_core<0>(As, Bs, A, wk, bk, Ko, 1.f);
  else             gemm_core<1>(As, Bs, A, wv, bv, Vo, 1.f);
}

__global__ __launch_bounds__(256) void k_gemm_o(
    const u16* __restrict__ A, const u16* __restrict__ wo,
    const float* __restrict__ bo, float* __restrict__ out) {
  __shared__ __attribute__((aligned(16))) u16 As[128 * 32];
  __shared__ __attribute__((aligned(16))) u16 Bs[128 * 32];
  gemm_core<2>(As, Bs, A, wo, bo, out, 1.f);
}

// ---- flash attention: Q,K [H][S][64] (Q pre-scaled by CEXP), Vt [H][64][S]
// -> Aout bf16 [S][DM].  32x32x16 MFMA; in-register softmax (no max tracking,
// cvt_pk+permlane P pack, ones-MFMA denominator).  Triple-buffered K/V with a
// SINGLE barrier per tile (3 bufs => stage(t+1) can't collide with a laggard
// wave reading t-1); all 16 fragment ds_reads hoisted to tile top.
__global__ __launch_bounds__(256, 2) void k_attn(
    const u16* __restrict__ Q, const u16* __restrict__ Kg,
    const u16* __restrict__ Vt, u16* __restrict__ Aout) {
  __shared__ __attribute__((aligned(16))) u16 Ks[3][64 * 64];
  __shared__ __attribute__((aligned(16))) u16 Vs[3][64 * 64];

  const int tid = threadIdx.x;
  const int lane = tid & 63, wave = tid >> 6;
  const int l31 = lane & 31, lh = lane >> 5;

  // XCD-aware remap: 2 heads per XCD (K/V ~2MB fits one L2)
  const int id = blockIdx.x;
  const int xcd = id & 7, s = id >> 3;
  const int h = xcd * 2 + (s & 1);
  const int qb = s >> 1;
  const int q0 = qb * 128 + wave * 32;

  const u16* Qh = Q + (size_t)h * S_LEN * HDIM;
  const u16* Kh = Kg + (size_t)h * S_LEN * HDIM;
  const u16* Vh = Vt + (size_t)h * HDIM * S_LEN;

  // Q B-frags: col q = l31, k = ks*16 + lh*8 + e
  v8s qf[4];
#pragma unroll
  for (int ks = 0; ks < 4; ++ks)
    qf[ks] = *reinterpret_cast<const v8s*>(
        Qh + (size_t)(q0 + l31) * HDIM + ks * 16 + lh * 8);

  const short ONE = 0x3F80;  // bf16 1.0
  const v8s ones = {ONE, ONE, ONE, ONE, ONE, ONE, ONE, ONE};

  f32x16 oacc[2], accl;
  oacc[0] = vzero16(); oacc[1] = vzero16(); accl = vzero16();

  // staging map: tile [64 rows][8 chunks of 16B], chunk ^= row&7
  const int s0i = tid, s1i = tid + 256;
  const int r0 = s0i >> 3, c0 = ((s0i & 7) ^ (r0 & 7)) * 8;
  const int r1 = s1i >> 3, c1 = ((s1i & 7) ^ (r1 & 7)) * 8;

  auto stageKV = [&](int b, int t) {
    const int kv0 = t * 64;
    gstage16(Kh + (size_t)(kv0 + r0) * HDIM + c0, &Ks[b][(wave * 64) * 8]);
    gstage16(Kh + (size_t)(kv0 + r1) * HDIM + c1, &Ks[b][(256 + wave * 64) * 8]);
    gstage16(Vh + (size_t)r0 * S_LEN + kv0 + c0, &Vs[b][(wave * 64) * 8]);
    gstage16(Vh + (size_t)r1 * S_LEN + kv0 + c1, &Vs[b][(256 + wave * 64) * 8]);
  };

  stageKV(0, 0);
  int cur = 0;

  constexpr int NT = S_LEN / 64;
  for (int t = 0; t < NT; ++t) {
    const int nxt = (cur == 2) ? 0 : cur + 1;
    if (t + 1 < NT) {
      stageKV(nxt, t + 1);
      // wait own tile-t loads (4 newest = tile t+1 stay in flight), then join
      asm volatile("s_waitcnt vmcnt(4)\n\ts_barrier" ::: "memory");
    } else {
      asm volatile("s_waitcnt vmcnt(0)\n\ts_barrier" ::: "memory");
    }
    const u16* Kb = &Ks[cur][0];
    const u16* Vb = &Vs[cur][0];

    // hoist ALL fragment reads: compiler pipelines lgkmcnt under the MFMAs
    v8s kf[2][4], vf[2][4];
#pragma unroll
    for (int j = 0; j < 2; ++j) {
      const int row = j * 32 + l31;
#pragma unroll
      for (int ks = 0; ks < 4; ++ks)
        kf[j][ks] = *reinterpret_cast<const v8s*>(
            Kb + (size_t)(row * 8 + (((ks * 2) + lh) ^ (row & 7))) * 8);
    }
#pragma unroll
    for (int n = 0; n < 2; ++n) {
      const int row = n * 32 + l31;
#pragma unroll
      for (int ks = 0; ks < 4; ++ks)
        vf[n][ks] = *reinterpret_cast<const v8s*>(
            Vb + (size_t)(row * 8 + (((ks * 2) + lh) ^ (row & 7))) * 8);
    }

    // S^T = K @ Q^T: per C-tile j (kv block of 32): row=kv, col=q
    f32x16 sacc[2];
    sacc[0] = vzero16(); sacc[1] = vzero16();
    __builtin_amdgcn_s_setprio(1);
#pragma unroll
    for (int ks = 0; ks < 4; ++ks) {
      sacc[0] = __builtin_amdgcn_mfma_f32_32x32x16_bf16(kf[0][ks], qf[ks], sacc[0], 0, 0, 0);
      sacc[1] = __builtin_amdgcn_mfma_f32_32x32x16_bf16(kf[1][ks], qf[ks], sacc[1], 0, 0, 0);
    }
    __builtin_amdgcn_s_setprio(0);

    // p = exp2(s); pack to PV A-frags fully in-register
    v8s pf[4];
#pragma unroll
    for (int j = 0; j < 2; ++j) {
      float p[16];
#pragma unroll
      for (int r = 0; r < 16; ++r) p[r] = exp2f(sacc[j][r]);
      u32 X1, X2, X3, X4, Y1, Y2, Y3, Y4;
      asm("v_cvt_pk_bf16_f32 %0, %1, %2" : "=v"(X1) : "v"(p[0]), "v"(p[1]));
      asm("v_cvt_pk_bf16_f32 %0, %1, %2" : "=v"(Y1) : "v"(p[4]), "v"(p[5]));
      asm("v_cvt_pk_bf16_f32 %0, %1, %2" : "=v"(X2) : "v"(p[2]), "v"(p[3]));
      asm("v_cvt_pk_bf16_f32 %0, %1, %2" : "=v"(Y2) : "v"(p[6]), "v"(p[7]));
      asm("v_cvt_pk_bf16_f32 %0, %1, %2" : "=v"(X3) : "v"(p[8]), "v"(p[9]));
      asm("v_cvt_pk_bf16_f32 %0, %1, %2" : "=v"(Y3) : "v"(p[12]), "v"(p[13]));
      asm("v_cvt_pk_bf16_f32 %0, %1, %2" : "=v"(X4) : "v"(p[10]), "v"(p[11]));
      asm("v_cvt_pk_bf16_f32 %0, %1, %2" : "=v"(Y4) : "v"(p[14]), "v"(p[15]));
      asm("v_permlane32_swap_b32 %0, %1" : "+v"(X1), "+v"(Y1));
      asm("v_permlane32_swap_b32 %0, %1" : "+v"(X2), "+v"(Y2));
      asm("v_permlane32_swap_b32 %0, %1" : "+v"(X3), "+v"(Y3));
      asm("v_permlane32_swap_b32 %0, %1" : "+v"(X4), "+v"(Y4));
      uint4 w0; w0.x = X1; w0.y = X2; w0.z = Y1; w0.w = Y2;
      uint4 w1; w1.x = X3; w1.y = X4; w1.z = Y3; w1.w = Y4;
      pf[j * 2 + 0] = *reinterpret_cast<const v8s*>(&w0);
      pf[j * 2 + 1] = *reinterpret_cast<const v8s*>(&w1);
    }

    // PV: O[q][hd] += P[q][kv] @ V[kv][hd]; l[q] += P @ 1
    __builtin_amdgcn_s_setprio(1);
#pragma unroll
    for (int ks = 0; ks < 4; ++ks) {
      accl = __builtin_amdgcn_mfma_f32_32x32x16_bf16(pf[ks], ones, accl, 0, 0, 0);
      oacc[0] = __builtin_amdgcn_mfma_f32_32x32x16_bf16(pf[ks], vf[0][ks], oacc[0], 0, 0, 0);
      oacc[1] = __builtin_amdgcn_mfma_f32_32x32x16_bf16(pf[ks], vf[1][ks], oacc[1], 0, 0, 0);
    }
    __builtin_amdgcn_s_setprio(0);
    cur = nxt;  // no end barrier: 3 buffers + <1-iter wave drift = race-free
  }

  // finalize: rows of oacc/accl are q = (r&3) + 8*(r>>2) + 4*lh (+q0)
#pragma unroll
  for (int r = 0; r < 16; ++r) {
    const float inv = __builtin_amdgcn_rcpf(accl[r]);
    const int q = q0 + (r & 3) + 8 * (r >> 2) + 4 * lh;
    const size_t base = (size_t)q * DM + h * HDIM + l31;
    Aout[base] = f2bs(oacc[0][r] * inv);
    Aout[base + 32] = f2bs(oacc[1][r] * inv);
  }
}

// ---- launcher ----------------------------------------------------------
extern "C" void kernel_launch(void* const* d_in, const int* in_sizes, int n_in,
                              void* d_out, int out_size, void* d_ws, size_t ws_size,
                              hipStream_t stream) {
  const float* x  = (const float*)d_in[0];
  const float* wq = (const float*)d_in[1];
  const float* bq = (const float*)d_in[2];
  const float* wk = (const float*)d_in[3];
  const float* bk = (const float*)d_in[4];
  const float* wv = (const float*)d_in[5];
  const float* bv = (const float*)d_in[6];
  const float* wo = (const float*)d_in[7];
  const float* bo = (const float*)d_in[8];
  float* out = (float*)d_out;

  char* ws = (char*)d_ws;
  u16* xb  = (u16*)(ws);                          // [4096][1024] bf16, 8MB
  u16* wqT = (u16*)(ws + (8u << 20));             // [1024][1024] bf16, 2MB each
  u16* wkT = wqT + 1024 * 1024;
  u16* wvT = wkT + 1024 * 1024;
  u16* woT = wvT + 1024 * 1024;
  u16* Qh  = (u16*)(ws + (16u << 20));            // [16][4096][64] bf16, 8MB
  u16* Kh  = Qh + 16 * 4096 * 64;
  u16* Vth = Kh + 16 * 4096 * 64;                 // [16][64][4096]
  u16* Ao  = Vth + 16 * 4096 * 64;                // [4096][1024]

  k_cvt<<<2048, 256, 0, stream>>>(x, xb);
  dim3 tg(32, 32, 4);
  k_wtrans<<<tg, 256, 0, stream>>>(wq, wk, wv, wo, wqT, wkT, wvT, woT);
  dim3 gg(32, 8, 3);
  k_gemm_qkv<<<gg, 256, 0, stream>>>(xb, wqT, wkT, wvT, bq, bk, bv, Qh, Kh, Vth);
  k_attn<<<512, 256, 0, stream>>>(Qh, Kh, Vth, Ao);
  dim3 og(32, 8);
  k_gemm_o<<<og, 256, 0, stream>>>(Ao, woT, bo, out);
}

// Round 5
// 167.706 us; speedup vs baseline: 1.1923x; 1.1923x over previous
//
#include <hip/hip_runtime.h>

typedef unsigned short u16;
typedef unsigned int u32;
typedef short v8s __attribute__((ext_vector_type(8)));
typedef float f32x4 __attribute__((ext_vector_type(4)));
typedef float f32x16 __attribute__((ext_vector_type(16)));

#define S_LEN 4096
#define DM 1024
#define HDIM 64
#define CEXP 0.18033688f /* 0.125 * log2(e), folded into Q at GEMM epilogue */

// ---- helpers ----------------------------------------------------------
__device__ __forceinline__ u16 f2bs(float f) {
  u32 u = __float_as_uint(f);
  u32 r = 0x7FFFu + ((u >> 16) & 1u);
  return (u16)((u + r) >> 16);
}

__device__ __forceinline__ float fexp2(float x) {
  float r;
  asm("v_exp_f32 %0, %1" : "=v"(r) : "v"(x));   // raw 2^x, args bounded
  return r;
}

__device__ __forceinline__ void gstage16(const void* g, void* lds_wave_base) {
  __builtin_amdgcn_global_load_lds(
      (const __attribute__((address_space(1))) u32*)g,
      (__attribute__((address_space(3))) u32*)lds_wave_base, 16, 0, 0);
}

__device__ __forceinline__ f32x16 vzero16() {
  f32x16 v;
#pragma unroll
  for (int r = 0; r < 16; ++r) v[r] = 0.f;
  return v;
}

// ---- elementwise fp32 -> bf16 -----------------------------------------
__global__ void k_cvt(const float* __restrict__ in, u16* __restrict__ out) {
  const int i = blockIdx.x * blockDim.x + threadIdx.x;
  const float4* p = reinterpret_cast<const float4*>(in) + (size_t)i * 2;
  float4 a = p[0], b = p[1];
  u16 t[8] = {f2bs(a.x), f2bs(a.y), f2bs(a.z), f2bs(a.w),
              f2bs(b.x), f2bs(b.y), f2bs(b.z), f2bs(b.w)};
  reinterpret_cast<uint4*>(out)[i] = *reinterpret_cast<const uint4*>(t);
}

// ---- weight transpose+convert: w[K][N] fp32 -> wt[N][K] bf16 ----------
__global__ __launch_bounds__(256) void k_wtrans(
    const float* __restrict__ w0, const float* __restrict__ w1,
    const float* __restrict__ w2, const float* __restrict__ w3,
    u16* __restrict__ t0, u16* __restrict__ t1,
    u16* __restrict__ t2, u16* __restrict__ t3) {
  __shared__ float tile[32][33];
  const float* w; u16* wt;
  switch (blockIdx.z) {
    case 0: w = w0; wt = t0; break;
    case 1: w = w1; wt = t1; break;
    case 2: w = w2; wt = t2; break;
    default: w = w3; wt = t3; break;
  }
  const int r = threadIdx.x >> 3;
  const int c4 = (threadIdx.x & 7) * 4;
  const int k0 = blockIdx.x * 32, n0 = blockIdx.y * 32;
  float4 v = *reinterpret_cast<const float4*>(w + (size_t)(k0 + r) * DM + n0 + c4);
  tile[r][c4] = v.x; tile[r][c4 + 1] = v.y; tile[r][c4 + 2] = v.z; tile[r][c4 + 3] = v.w;
  __syncthreads();
  u16 o4[4] = {f2bs(tile[c4][r]), f2bs(tile[c4 + 1][r]),
               f2bs(tile[c4 + 2][r]), f2bs(tile[c4 + 3][r])};
  *reinterpret_cast<uint2*>(wt + (size_t)(n0 + r) * DM + k0 + c4) =
      *reinterpret_cast<const uint2*>(o4);
}

// ---- GEMM core: C[M=4096,N=1024] = A[bf16, M,K] @ Bt[bf16, N,K]^T + bias
template <int MODE>
__device__ __forceinline__ void gemm_core(
    u16* __restrict__ As, u16* __restrict__ Bs,
    const u16* __restrict__ A, const u16* __restrict__ Bt,
    const float* __restrict__ bias, void* __restrict__ Cout, float oscale) {
  constexpr int K = DM, N = DM;
  const int tid = threadIdx.x;
  const int lane = tid & 63, wave = tid >> 6;
  const int wm = wave >> 1, wn = wave & 1;
  const int l15 = lane & 15, l4 = lane >> 4;
  const int bm0 = blockIdx.x * 128, bn0 = blockIdx.y * 128;

  f32x4 acc[4][4];
#pragma unroll
  for (int m = 0; m < 4; ++m)
#pragma unroll
    for (int n = 0; n < 4; ++n) acc[m][n] = 0.f;

  const int s0 = tid, s1 = tid + 256;
  const int ra0 = s0 >> 2, ca0 = ((s0 & 3) ^ ((ra0 >> 1) & 3)) * 8;
  const int ra1 = s1 >> 2, ca1 = ((s1 & 3) ^ ((ra1 >> 1) & 3)) * 8;
  const u16* Ab = A + (size_t)bm0 * K;
  const u16* Bb = Bt + (size_t)bn0 * K;
  u16* ldsA0 = As + (size_t)(wave * 64) * 8;
  u16* ldsA1 = As + (size_t)(256 + wave * 64) * 8;
  u16* ldsB0 = Bs + (size_t)(wave * 64) * 8;
  u16* ldsB1 = Bs + (size_t)(256 + wave * 64) * 8;

  for (int k0 = 0; k0 < K; k0 += 32) {
    gstage16(Ab + (size_t)ra0 * K + k0 + ca0, ldsA0);
    gstage16(Ab + (size_t)ra1 * K + k0 + ca1, ldsA1);
    gstage16(Bb + (size_t)ra0 * K + k0 + ca0, ldsB0);
    gstage16(Bb + (size_t)ra1 * K + k0 + ca1, ldsB1);
    __syncthreads();
    v8s af[4], bfr[4];
#pragma unroll
    for (int m = 0; m < 4; ++m) {
      const int rowa = wm * 64 + m * 16 + l15;
      af[m] = *reinterpret_cast<const v8s*>(
          As + (size_t)(rowa * 4 + (l4 ^ ((rowa >> 1) & 3))) * 8);
      const int rowb = wn * 64 + m * 16 + l15;
      bfr[m] = *reinterpret_cast<const v8s*>(
          Bs + (size_t)(rowb * 4 + (l4 ^ ((rowb >> 1) & 3))) * 8);
    }
#pragma unroll
    for (int m = 0; m < 4; ++m)
#pragma unroll
      for (int n = 0; n < 4; ++n)
        acc[m][n] = __builtin_amdgcn_mfma_f32_16x16x32_bf16(af[m], bfr[n], acc[m][n], 0, 0, 0);
    __syncthreads();
  }

#pragma unroll
  for (int m = 0; m < 4; ++m) {
    const int gs0 = bm0 + wm * 64 + m * 16 + l4 * 4;
#pragma unroll
    for (int n = 0; n < 4; ++n) {
      const int gn = bn0 + wn * 64 + n * 16 + l15;
      const float bv = bias[gn];
      if (MODE == 0) {
        u16* O = (u16*)Cout;
        const size_t base = (size_t)(gn >> 6) * (S_LEN * HDIM) + (size_t)(gn & 63);
#pragma unroll
        for (int r = 0; r < 4; ++r)
          O[base + (size_t)(gs0 + r) * HDIM] = f2bs((acc[m][n][r] + bv) * oscale);
      } else if (MODE == 1) {
        u16* O = (u16*)Cout;
        u16 p4[4];
#pragma unroll
        for (int r = 0; r < 4; ++r) p4[r] = f2bs(acc[m][n][r] + bv);
        *reinterpret_cast<uint2*>(O + (size_t)(gn >> 6) * (HDIM * S_LEN) +
                                  (size_t)(gn & 63) * S_LEN + gs0) =
            *reinterpret_cast<const uint2*>(p4);
      } else {
        float* O = (float*)Cout;
#pragma unroll
        for (int r = 0; r < 4; ++r)
          O[(size_t)(gs0 + r) * N + gn] = acc[m][n][r] + bv;
      }
    }
  }
}

__global__ __launch_bounds__(256) void k_gemm_qkv(
    const u16* __restrict__ A,
    const u16* __restrict__ wq, const u16* __restrict__ wk, const u16* __restrict__ wv,
    const float* __restrict__ bq, const float* __restrict__ bk, const float* __restrict__ bv,
    u16* __restrict__ Qo, u16* __restrict__ Ko, u16* __restrict__ Vo) {
  __shared__ __attribute__((aligned(16))) u16 As[128 * 32];
  __shared__ __attribute__((aligned(16))) u16 Bs[128 * 32];
  const int z = blockIdx.z;
  if (z == 0)      gemm_core<0>(As, Bs, A, wq, bq, Qo, CEXP);
  else if (z == 1) gemm_core<0>(As, Bs, A, wk, bk, Ko, 1.f);
  else             gemm_core<1>(As, Bs, A, wv, bv, Vo, 1.f);
}

__global__ __launch_bounds__(256) void k_gemm_o(
    const u16* __restrict__ A, const u16* __restrict__ wo,
    const float* __restrict__ bo, float* __restrict__ out) {
  __shared__ __attribute__((aligned(16))) u16 As[128 * 32];
  __shared__ __attribute__((aligned(16))) u16 Bs[128 * 32];
  gemm_core<2>(As, Bs, A, wo, bo, out, 1.f);
}

// ---- flash attention: Q,K [H][S][64] (Q pre-scaled by CEXP), Vt [H][64][S]
// -> Aout bf16 [S][DM].
// Software-pipelined: QK(t+1) on the MFMA pipe overlaps softmax(t) on the
// VALU pipe (ping-ponged S accumulators, unroll-2, static names).
// Triple-buffered K/V; ONE barrier per tile; stage(t+2) issued after the
// barrier (all waves past barrier(t) have finished PV(t-1) => buf free).
__global__ __launch_bounds__(256, 2) void k_attn(
    const u16* __restrict__ Q, const u16* __restrict__ Kg,
    const u16* __restrict__ Vt, u16* __restrict__ Aout) {
  __shared__ __attribute__((aligned(16))) u16 Ks[3][64 * 64];
  __shared__ __attribute__((aligned(16))) u16 Vs[3][64 * 64];

  const int tid = threadIdx.x;
  const int lane = tid & 63, wave = tid >> 6;
  const int l31 = lane & 31, lh = lane >> 5;

  // XCD-aware remap: 2 heads per XCD (K/V ~2MB fits one L2)
  const int id = blockIdx.x;
  const int xcd = id & 7, sp = id >> 3;
  const int h = xcd * 2 + (sp & 1);
  const int qb = sp >> 1;
  const int q0 = qb * 128 + wave * 32;

  const u16* Qh = Q + (size_t)h * S_LEN * HDIM;
  const u16* Kh = Kg + (size_t)h * S_LEN * HDIM;
  const u16* Vh = Vt + (size_t)h * HDIM * S_LEN;

  // Q B-frags: col q = l31, k = ks*16 + lh*8 + e
  v8s qf[4];
#pragma unroll
  for (int ks = 0; ks < 4; ++ks)
    qf[ks] = *reinterpret_cast<const v8s*>(
        Qh + (size_t)(q0 + l31) * HDIM + ks * 16 + lh * 8);

  const short ONE = 0x3F80;  // bf16 1.0
  const v8s ones = {ONE, ONE, ONE, ONE, ONE, ONE, ONE, ONE};
  const f32x16 z16 = vzero16();   // persistent zero C-operand (kills 32 movs/tile)

  f32x16 oacc[2], accl;
  oacc[0] = z16; oacc[1] = z16; accl = z16;

  // staging map: tile [64 rows][8 chunks of 16B], chunk ^= row&7
  const int s0i = tid, s1i = tid + 256;
  const int r0 = s0i >> 3, c0 = ((s0i & 7) ^ (r0 & 7)) * 8;
  const int r1 = s1i >> 3, c1 = ((s1i & 7) ^ (r1 & 7)) * 8;

  auto stageKV = [&](int b, int t) {
    const int kv0 = t * 64;
    gstage16(Kh + (size_t)(kv0 + r0) * HDIM + c0, &Ks[b][(wave * 64) * 8]);
    gstage16(Kh + (size_t)(kv0 + r1) * HDIM + c1, &Ks[b][(256 + wave * 64) * 8]);
    gstage16(Vh + (size_t)r0 * S_LEN + kv0 + c0, &Vs[b][(wave * 64) * 8]);
    gstage16(Vh + (size_t)r1 * S_LEN + kv0 + c1, &Vs[b][(256 + wave * 64) * 8]);
  };

  // QK into sO from LDS buffer Kb (C = z16 on first MFMA)
  auto qk = [&](const u16* Kb, f32x16 (&sO)[2]) {
    __builtin_amdgcn_s_setprio(1);
#pragma unroll
    for (int j = 0; j < 2; ++j) {
      const int row = j * 32 + l31;
      v8s k0 = *reinterpret_cast<const v8s*>(
          Kb + (size_t)(row * 8 + ((0 + lh) ^ (row & 7))) * 8);
      sO[j] = __builtin_amdgcn_mfma_f32_32x32x16_bf16(k0, qf[0], z16, 0, 0, 0);
#pragma unroll
      for (int ks = 1; ks < 4; ++ks) {
        v8s kf = *reinterpret_cast<const v8s*>(
            Kb + (size_t)(row * 8 + ((ks * 2 + lh) ^ (row & 7))) * 8);
        sO[j] = __builtin_amdgcn_mfma_f32_32x32x16_bf16(kf, qf[ks], sO[j], 0, 0, 0);
      }
    }
    __builtin_amdgcn_s_setprio(0);
  };

  // body(t): [wait+barrier] stage(t+2); QK(t+1)->sOut; softmax(sIn)->pf; PV(t)
  auto body = [&](int t, int ib, f32x16 (&sIn)[2], f32x16 (&sOut)[2],
                  bool hasNext, bool hasNext2) {
    asm volatile("s_waitcnt vmcnt(0)\n\ts_barrier" ::: "memory");
    if (hasNext2) stageKV(ib == 0 ? 2 : ib - 1, t + 2);      // (t+2)%3
    if (hasNext) qk(&Ks[ib == 2 ? 0 : ib + 1][0], sOut);     // (t+1)%3

    // V fragment reads issued now: latency hides under the exp/pack VALU
    const u16* Vb = &Vs[ib][0];
    v8s vf[2][4];
#pragma unroll
    for (int n = 0; n < 2; ++n) {
      const int row = n * 32 + l31;
#pragma unroll
      for (int ks = 0; ks < 4; ++ks)
        vf[n][ks] = *reinterpret_cast<const v8s*>(
            Vb + (size_t)(row * 8 + ((ks * 2 + lh) ^ (row & 7))) * 8);
    }

    // softmax(sIn): p = exp2(s); pack to PV A-frags fully in-register
    v8s pf[4];
#pragma unroll
    for (int j = 0; j < 2; ++j) {
      float p[16];
#pragma unroll
      for (int r = 0; r < 16; ++r) p[r] = fexp2(sIn[j][r]);
      u32 X1, X2, X3, X4, Y1, Y2, Y3, Y4;
      asm("v_cvt_pk_bf16_f32 %0, %1, %2" : "=v"(X1) : "v"(p[0]), "v"(p[1]));
      asm("v_cvt_pk_bf16_f32 %0, %1, %2" : "=v"(Y1) : "v"(p[4]), "v"(p[5]));
      asm("v_cvt_pk_bf16_f32 %0, %1, %2" : "=v"(X2) : "v"(p[2]), "v"(p[3]));
      asm("v_cvt_pk_bf16_f32 %0, %1, %2" : "=v"(Y2) : "v"(p[6]), "v"(p[7]));
      asm("v_cvt_pk_bf16_f32 %0, %1, %2" : "=v"(X3) : "v"(p[8]), "v"(p[9]));
      asm("v_cvt_pk_bf16_f32 %0, %1, %2" : "=v"(Y3) : "v"(p[12]), "v"(p[13]));
      asm("v_cvt_pk_bf16_f32 %0, %1, %2" : "=v"(X4) : "v"(p[10]), "v"(p[11]));
      asm("v_cvt_pk_bf16_f32 %0, %1, %2" : "=v"(Y4) : "v"(p[14]), "v"(p[15]));
      asm("v_permlane32_swap_b32 %0, %1" : "+v"(X1), "+v"(Y1));
      asm("v_permlane32_swap_b32 %0, %1" : "+v"(X2), "+v"(Y2));
      asm("v_permlane32_swap_b32 %0, %1" : "+v"(X3), "+v"(Y3));
      asm("v_permlane32_swap_b32 %0, %1" : "+v"(X4), "+v"(Y4));
      uint4 w0; w0.x = X1; w0.y = X2; w0.z = Y1; w0.w = Y2;
      uint4 w1; w1.x = X3; w1.y = X4; w1.z = Y3; w1.w = Y4;
      pf[j * 2 + 0] = *reinterpret_cast<const v8s*>(&w0);
      pf[j * 2 + 1] = *reinterpret_cast<const v8s*>(&w1);
    }

    // PV: O[q][hd] += P[q][kv] @ V[kv][hd]; l[q] += P @ 1
    __builtin_amdgcn_s_setprio(1);
#pragma unroll
    for (int ks = 0; ks < 4; ++ks) {
      accl = __builtin_amdgcn_mfma_f32_32x32x16_bf16(pf[ks], ones, accl, 0, 0, 0);
      oacc[0] = __builtin_amdgcn_mfma_f32_32x32x16_bf16(pf[ks], vf[0][ks], oacc[0], 0, 0, 0);
      oacc[1] = __builtin_amdgcn_mfma_f32_32x32x16_bf16(pf[ks], vf[1][ks], oacc[1], 0, 0, 0);
    }
    __builtin_amdgcn_s_setprio(0);
  };

  constexpr int NT = S_LEN / 64;
  f32x16 sacc0[2], sacc1[2];

  // prologue: stage tiles 0,1; wait tile0; QK(0)->sacc0
  stageKV(0, 0);
  stageKV(1, 1);
  asm volatile("s_waitcnt vmcnt(4)\n\ts_barrier" ::: "memory");
  qk(&Ks[0][0], sacc0);

  int ib = 0;
  for (int tt = 0; tt < NT - 2; tt += 2) {
    body(tt, ib, sacc0, sacc1, true, true);
    const int ib1 = (ib == 2) ? 0 : ib + 1;
    body(tt + 1, ib1, sacc1, sacc0, true, true);
    ib += 2; if (ib >= 3) ib -= 3;
  }
  body(NT - 2, ib, sacc0, sacc1, true, false);
  const int ibL = (ib == 2) ? 0 : ib + 1;
  body(NT - 1, ibL, sacc1, sacc0, false, false);

  // finalize: rows of oacc/accl are q = (r&3) + 8*(r>>2) + 4*lh (+q0)
#pragma unroll
  for (int r = 0; r < 16; ++r) {
    const float inv = __builtin_amdgcn_rcpf(accl[r]);
    const int q = q0 + (r & 3) + 8 * (r >> 2) + 4 * lh;
    const size_t base = (size_t)q * DM + h * HDIM + l31;
    Aout[base] = f2bs(oacc[0][r] * inv);
    Aout[base + 32] = f2bs(oacc[1][r] * inv);
  }
}

// ---- launcher ----------------------------------------------------------
extern "C" void kernel_launch(void* const* d_in, const int* in_sizes, int n_in,
                              void* d_out, int out_size, void* d_ws, size_t ws_size,
                              hipStream_t stream) {
  const float* x  = (const float*)d_in[0];
  const float* wq = (const float*)d_in[1];
  const float* bq = (const float*)d_in[2];
  const float* wk = (const float*)d_in[3];
  const float* bk = (const float*)d_in[4];
  const float* wv = (const float*)d_in[5];
  const float* bv = (const float*)d_in[6];
  const float* wo = (const float*)d_in[7];
  const float* bo = (const float*)d_in[8];
  float* out = (float*)d_out;

  char* ws = (char*)d_ws;
  u16* xb  = (u16*)(ws);                          // [4096][1024] bf16, 8MB
  u16* wqT = (u16*)(ws + (8u << 20));             // [1024][1024] bf16, 2MB each
  u16* wkT = wqT + 1024 * 1024;
  u16* wvT = wkT + 1024 * 1024;
  u16* woT = wvT + 1024 * 1024;
  u16* Qh  = (u16*)(ws + (16u << 20));            // [16][4096][64] bf16, 8MB
  u16* Kh  = Qh + 16 * 4096 * 64;
  u16* Vth = Kh + 16 * 4096 * 64;                 // [16][64][4096]
  u16* Ao  = Vth + 16 * 4096 * 64;                // [4096][1024]

  k_cvt<<<2048, 256, 0, stream>>>(x, xb);
  dim3 tg(32, 32, 4);
  k_wtrans<<<tg, 256, 0, stream>>>(wq, wk, wv, wo, wqT, wkT, wvT, woT);
  dim3 gg(32, 8, 3);
  k_gemm_qkv<<<gg, 256, 0, stream>>>(xb, wqT, wkT, wvT, bq, bk, bv, Qh, Kh, Vth);
  k_attn<<<512, 256, 0, stream>>>(Qh, Kh, Vth, Ao);
  dim3 og(32, 8);
  k_gemm_o<<<og, 256, 0, stream>>>(Ao, woT, bo, out);
}